// Round 11
// baseline (86.616 us; speedup 1.0000x reference)
//
#include <hip/hip_runtime.h>
#include <hip/hip_bf16.h>

// Shapes (fixed by setup_inputs): B=32, L=2048, V=30522, Dw=300, H=768, S=L/P=128
#define B_   32
#define L_   2048
#define V_   30522
#define DW   300
#define H_   768
#define KP   320              // Dw padded to multiple of 32 for MFMA K
#define NT   (H_/16)          // 48 n-tiles
#define KT   (KP/32)          // 10 k-tiles
#define VPAD 30528            // V rounded up; 30528 = 636 * 48 exactly
#define MB   48               // rows per block (3 m-tiles)
#define NW   6                // n-tiles per wave (8 waves x 6 = 48)
#define APAD 336              // padded LDS row stride (bf16): 672 B rows, 16B-aligned

typedef __attribute__((ext_vector_type(8))) short bf16x8;
typedef __attribute__((ext_vector_type(4))) float f32x4;

// ---------------- K0a: pack W [300][768] fp32 -> Wp bf16, fragment f = kt*NT + n --------------
__global__ void pack_w(const float* __restrict__ W, __hip_bfloat16* __restrict__ Wp) {
    int t = blockIdx.x * 256 + threadIdx.x;           // [0, NT*KT*64)
    if (t >= NT * KT * 64) return;
    int lane = t & 63;
    int f    = t >> 6;
    int n    = f % NT;
    int kt   = f / NT;
    int col  = n * 16 + (lane & 15);
    int k0   = kt * 32 + (lane >> 4) * 8;
    union { __hip_bfloat16 h[8]; int4 v; } u;
    #pragma unroll
    for (int j = 0; j < 8; ++j) {
        int k = k0 + j;
        float w = (k < DW) ? W[(size_t)k * H_ + col] : 0.f;
        u.h[j] = __float2bfloat16(w);
    }
    reinterpret_cast<int4*>(Wp)[t] = u.v;
}

// ---------------- K0b: h1 table [VPAD][KP] bf16 = LN1(emb_table) (one wave per vocab row) -----
__global__ void embed_ln1(const float* __restrict__ emb, const float* __restrict__ g1,
                          const float* __restrict__ b1, __hip_bfloat16* __restrict__ h1) {
    int wave = (blockIdx.x * blockDim.x + threadIdx.x) >> 6;
    int lane = threadIdx.x & 63;
    if (wave >= VPAD) return;
    __hip_bfloat16* dst = h1 + (size_t)wave * KP;
    if (wave >= V_) {                                  // zero pad rows
        for (int k = lane; k < KP; k += 64) dst[k] = __float2bfloat16(0.f);
        return;
    }
    const float* row = emb + (size_t)wave * DW;
    float x[5]; float s = 0.f, ss = 0.f;
    #pragma unroll
    for (int i = 0; i < 5; ++i) {                      // 5*64 = 320 covers KP exactly
        int k = lane + i * 64;
        float v = (k < DW) ? row[k] : 0.f;
        x[i] = v; s += v; ss += v * v;
    }
    #pragma unroll
    for (int m = 32; m >= 1; m >>= 1) { s += __shfl_xor(s, m); ss += __shfl_xor(ss, m); }
    float mu   = s / (float)DW;
    float var  = ss / (float)DW - mu * mu;
    float rstd = rsqrtf(var + 1e-12f);
    #pragma unroll
    for (int i = 0; i < 5; ++i) {
        int k = lane + i * 64;
        float o = (k < DW) ? (g1[k] * ((x[i] - mu) * rstd) + b1[k]) : 0.f;
        dst[k] = __float2bfloat16(o);
    }
}

// ---------------- K1: G[v] = LN2(relu(h1[v] @ W + b)) — depth-3 SW pipeline -------------------
// Block = 48 rows, 8 waves (512 thr); wave w owns n-tiles [w*6, w*6+6) for ALL 48 rows.
// bbuf[4]: B-prefetch 3 kt-steps ahead (latency budget = 3 compute steps); abuf[2]: A from
// LDS 1 step ahead. sched_barrier(0) pins prefetch above each MFMA cluster (r10-verified).
// Regs ~150 arch VGPR + 72 AGPR acc = ~222 -> same 2 waves/SIMD band as r10, 2x deeper pipe.
// C/D layout (m89-verified): col = lane&15, row = (lane>>4)*4 + reg.
__global__ void __launch_bounds__(512, 2)
gemm_ln2(const __hip_bfloat16* __restrict__ h1, const __hip_bfloat16* __restrict__ Wp,
         const float* __restrict__ bias, const float* __restrict__ g2,
         const float* __restrict__ b2, __hip_bfloat16* __restrict__ G) {
    __shared__ __hip_bfloat16 sA[MB * APAD];           // 32,256 B
    __shared__ float sred[2][8][MB];                   // 3 KB
    int tid  = threadIdx.x;
    int w    = tid >> 6;
    int lane = tid & 63;
    int r = lane & 15, q = lane >> 4;
    size_t row0 = (size_t)blockIdx.x * MB;

    // ---- stage A: 48 rows x 320 bf16 (30,720 B contiguous in h1) -> padded LDS ----
    const int4* gsrc = reinterpret_cast<const int4*>(h1 + row0 * KP);
    #pragma unroll
    for (int i = 0; i < 4; ++i) {
        int t4 = tid + i * 512;                        // int4 index, [0, 1920)
        if (t4 < MB * KP / 8) {
            int row = t4 / 40;                         // 40 int4 per row
            int col = (t4 % 40) * 8;
            *reinterpret_cast<int4*>(&sA[row * APAD + col]) = gsrc[t4];
        }
    }

    f32x4 acc[NW][3];
    #pragma unroll
    for (int nl = 0; nl < NW; ++nl)
        #pragma unroll
        for (int m = 0; m < 3; ++m) acc[nl][m] = (f32x4){0.f, 0.f, 0.f, 0.f};

    const bf16x8* Bv = reinterpret_cast<const bf16x8*>(Wp) + (size_t)w * NW * 64 + lane;
    const char* sAc = reinterpret_cast<const char*>(sA);
    const int abase = r * (APAD * 2) + q * 16;         // lane's A byte base (m=0, kt=0)
    int phase = (int)(blockIdx.x % KT);

    bf16x8 bbuf[4][NW];                                // 96 VGPR: 3-deep B prefetch
    bf16x8 abuf[2][3];                                 // 24 VGPR: 1-deep A (LDS) prefetch

    __syncthreads();                                   // sA ready
    // prologue: issue B for steps 0..2, A for step 0
    #pragma unroll
    for (int p = 0; p < 3; ++p) {
        int ktp = phase + p; if (ktp >= KT) ktp -= KT;
        const bf16x8* bp = Bv + (size_t)ktp * NT * 64;
        #pragma unroll
        for (int nl = 0; nl < NW; ++nl) bbuf[p][nl] = bp[nl * 64];
    }
    #pragma unroll
    for (int m = 0; m < 3; ++m)
        abuf[0][m] = *reinterpret_cast<const bf16x8*>(
            sAc + abase + m * (16 * APAD * 2) + phase * 64);

    #pragma unroll                                     // FULL unroll: all buf indices static
    for (int i = 0; i < KT; ++i) {
        const int cur = i & 3, acur = i & 1;
        if (i + 3 < KT) {                              // B prefetch, 3 steps ahead
            int ktn = phase + i + 3; if (ktn >= KT) ktn -= KT;
            const bf16x8* bp = Bv + (size_t)ktn * NT * 64;
            #pragma unroll
            for (int nl = 0; nl < NW; ++nl) bbuf[(i + 3) & 3][nl] = bp[nl * 64];
        }
        if (i + 1 < KT) {                              // A prefetch, 1 step ahead (LDS)
            int ktn = phase + i + 1; if (ktn >= KT) ktn -= KT;
            #pragma unroll
            for (int m = 0; m < 3; ++m)
                abuf[(i + 1) & 1][m] = *reinterpret_cast<const bf16x8*>(
                    sAc + abase + m * (16 * APAD * 2) + ktn * 64);
        }
        __builtin_amdgcn_sched_barrier(0);             // prefetch may NOT sink below MFMAs
        #pragma unroll
        for (int nl = 0; nl < NW; ++nl) {
            acc[nl][0] = __builtin_amdgcn_mfma_f32_16x16x32_bf16(abuf[acur][0], bbuf[cur][nl], acc[nl][0], 0, 0, 0);
            acc[nl][1] = __builtin_amdgcn_mfma_f32_16x16x32_bf16(abuf[acur][1], bbuf[cur][nl], acc[nl][1], 0, 0, 0);
            acc[nl][2] = __builtin_amdgcn_mfma_f32_16x16x32_bf16(abuf[acur][2], bbuf[cur][nl], acc[nl][2], 0, 0, 0);
        }
    }

    // bias + relu + in-wave partial stats (over this wave's 96 cols)
    float s_[3][4], ss_[3][4];
    #pragma unroll
    for (int m = 0; m < 3; ++m)
        #pragma unroll
        for (int j = 0; j < 4; ++j) { s_[m][j] = 0.f; ss_[m][j] = 0.f; }
    #pragma unroll
    for (int nl = 0; nl < NW; ++nl) {
        float bn = bias[w * 96 + nl * 16 + r];
        #pragma unroll
        for (int m = 0; m < 3; ++m)
            #pragma unroll
            for (int j = 0; j < 4; ++j) {
                float v = acc[nl][m][j] + bn;
                v = v > 0.f ? v : 0.f;
                acc[nl][m][j] = v;
                s_[m][j] += v; ss_[m][j] += v * v;
            }
    }
    #pragma unroll
    for (int msk = 1; msk < 16; msk <<= 1)             // reduce across the 16 r-lanes
        #pragma unroll
        for (int m = 0; m < 3; ++m)
            #pragma unroll
            for (int j = 0; j < 4; ++j) {
                s_[m][j]  += __shfl_xor(s_[m][j],  msk);
                ss_[m][j] += __shfl_xor(ss_[m][j], msk);
            }
    if (r == 0) {                                      // publish wave partials
        #pragma unroll
        for (int m = 0; m < 3; ++m)
            #pragma unroll
            for (int j = 0; j < 4; ++j) {
                int row = m * 16 + q * 4 + j;
                sred[0][w][row] = s_[m][j];
                sred[1][w][row] = ss_[m][j];
            }
    }
    __syncthreads();

    #pragma unroll
    for (int m = 0; m < 3; ++m) {
        #pragma unroll
        for (int j = 0; j < 4; ++j) {
            int row = m * 16 + q * 4 + j;
            float ts = 0.f, tss = 0.f;
            #pragma unroll
            for (int ww = 0; ww < 8; ++ww) { ts += sred[0][ww][row]; tss += sred[1][ww][row]; }
            float mu   = ts / (float)H_;
            float var  = tss / (float)H_ - mu * mu;
            float rstd = rsqrtf(var + 1e-12f);
            s_[m][j]  = mu;                            // reuse as mu
            ss_[m][j] = rstd;                          // reuse as rstd
        }
    }
    #pragma unroll
    for (int nl = 0; nl < NW; ++nl) {
        int col = w * 96 + nl * 16 + r;
        float gg = g2[col], bb = b2[col];
        #pragma unroll
        for (int m = 0; m < 3; ++m)
            #pragma unroll
            for (int j = 0; j < 4; ++j) {
                size_t rowg = row0 + m * 16 + q * 4 + j;
                float val = gg * (acc[nl][m][j] - s_[m][j]) * ss_[m][j] + bb;
                G[rowg * H_ + col] = __float2bfloat16(val);
            }
    }
}

// ---------------- K1.5: per-batch-row separator positions (general mask handling) -------------
__global__ void sep_scan(const int* __restrict__ sep, int* __restrict__ pos, int* __restrict__ nsep) {
    int b = blockIdx.x;
    const int* row = sep + (size_t)b * L_;
    __shared__ int cnt[256];
    int tid = threadIdx.x;
    int local[8]; int c = 0;
    #pragma unroll
    for (int i = 0; i < 8; ++i) { int v = row[tid * 8 + i]; local[i] = v; c += v; }
    cnt[tid] = c; __syncthreads();
    for (int ofs = 1; ofs < 256; ofs <<= 1) {          // Hillis-Steele inclusive scan
        int v = (tid >= ofs) ? cnt[tid - ofs] : 0;
        __syncthreads();
        cnt[tid] += v;
        __syncthreads();
    }
    int w = cnt[tid] - c;                              // exclusive prefix
    #pragma unroll
    for (int i = 0; i < 8; ++i)
        if (local[i]) { pos[(size_t)b * L_ + w] = tid * 8 + i; ++w; }
    if (tid == 255) nsep[b] = cnt[255];
}

// ---------------- K1.6: sinusoidal PE table [S][H] f32 (trig hoisted out of seg_gather) -------
__global__ void pe_table(float* __restrict__ PE, int S) {
    int t = blockIdx.x * 256 + threadIdx.x;
    if (t >= S * H_) return;
    int s = t / H_, n = t % H_;
    const float cexp = -9.210340371976184f / (float)H_;   // -ln(10000)/H
    float div = expf((float)(2 * (n >> 1)) * cexp);
    float ang = (float)s * div;
    PE[t] = (n & 1) ? cosf(ang) : sinf(ang);
}

// ---------------- K2: out[b,s,:] = mean_{t in seg(b,s)} G[ids[b,t]] + PE[s] -------------------
// 256 thr: two 96-lane groups process alternate tokens with int4 (16B/lane) gathers of G
// rows (8 bf16/lane), LDS-combine, PE added from table. Replaces 45 scalar 2B loads +
// ~6 transcendentals per thread (Common-mistake #2 + trig-table rule).
__global__ void seg_gather(const int* __restrict__ ids, const int* __restrict__ pos,
                           const int* __restrict__ nsep, const __hip_bfloat16* __restrict__ G,
                           const float* __restrict__ PE, float* __restrict__ out, int S) {
    int blk = blockIdx.x;
    int s = blk % S, b = blk / S;
    int tid = threadIdx.x;
    int g = tid / 96, l = tid - g * 96;                // g in {0,1}; g==2 lanes idle for loads
    int ns = nsep[b];
    int lo, hi;
    if (s > ns) { lo = 1; hi = 0; }                    // empty segment
    else {
        lo = (s == 0) ? 0 : pos[(size_t)b * L_ + (s - 1)] + 1;
        hi = (s < ns) ? pos[(size_t)b * L_ + s] - 1 : L_ - 1;   // s==ns: tail after last sep
    }
    int cnt = hi - lo + 1; if (cnt < 0) cnt = 0;

    float a[8] = {0.f, 0.f, 0.f, 0.f, 0.f, 0.f, 0.f, 0.f};
    if (g < 2) {
        for (int t = lo + g; t <= hi; t += 2) {
            int v = ids[(size_t)b * L_ + t];
            int4 raw = *reinterpret_cast<const int4*>(G + (size_t)v * H_ + l * 8);
            const unsigned short* u = reinterpret_cast<const unsigned short*>(&raw);
            #pragma unroll
            for (int k = 0; k < 8; ++k) {
                union { unsigned int i; float f; } c; c.i = ((unsigned int)u[k]) << 16;
                a[k] += c.f;
            }
        }
    }
    __shared__ float red[96 * 8];                      // 3 KB
    if (g == 1) {
        #pragma unroll
        for (int k = 0; k < 8; ++k) red[l * 8 + k] = a[k];
    }
    __syncthreads();
    if (g == 0) {
        float inv = (cnt > 0) ? 1.f / (float)cnt : 0.f;
        float* orow = out + ((size_t)b * S + s) * H_;
        const float* pe = PE + (size_t)s * H_;
        #pragma unroll
        for (int k = 0; k < 8; ++k) {
            int n = l * 8 + k;
            orow[n] = (a[k] + red[l * 8 + k]) * inv + pe[n];
        }
    }
}

// ---------------- host launcher ----------------
extern "C" void kernel_launch(void* const* d_in, const int* in_sizes, int n_in,
                              void* d_out, int out_size, void* d_ws, size_t ws_size,
                              hipStream_t stream) {
    const int*   ids  = (const int*)d_in[0];
    const int*   sep  = (const int*)d_in[1];
    const float* emb  = (const float*)d_in[3];
    const float* g1   = (const float*)d_in[4];
    const float* b1   = (const float*)d_in[5];
    const float* W    = (const float*)d_in[6];
    const float* bias = (const float*)d_in[7];
    const float* g2   = (const float*)d_in[8];
    const float* b2   = (const float*)d_in[9];
    float* out = (float*)d_out;

    int S = out_size / (B_ * H_);                      // 128

    // workspace layout (all offsets 16B-aligned)
    char* ws = (char*)d_ws;
    __hip_bfloat16* Wp  = (__hip_bfloat16*)(ws);                         // 491,520 B
    __hip_bfloat16* h1  = (__hip_bfloat16*)(ws + 491520);                // 19,537,920 B
    __hip_bfloat16* G   = (__hip_bfloat16*)(ws + 491520 + 19537920);     // 46,891,008 B
    int*   pos  = (int*)(ws + 491520 + 19537920 + 46891008);             // 262,144 B
    int*   nsep = (int*)(ws + 491520 + 19537920 + 46891008 + 262144);    // 256 B
    float* PE   = (float*)(ws + 491520 + 19537920 + 46891008 + 262144 + 256); // 393,216 B
    (void)ws_size; (void)n_in; (void)in_sizes;

    pack_w   <<<(NT * KT * 64 + 255) / 256, 256, 0, stream>>>(W, Wp);
    pe_table <<<(S * H_ + 255) / 256, 256, 0, stream>>>(PE, S);
    embed_ln1<<<VPAD / 4, 256, 0, stream>>>(emb, g1, b1, h1);
    gemm_ln2 <<<VPAD / MB, 512, 0, stream>>>(h1, Wp, bias, g2, b2, G);
    sep_scan <<<B_, 256, 0, stream>>>(sep, pos, nsep);
    seg_gather<<<B_ * S, 256, 0, stream>>>(ids, pos, nsep, G, PE, out, S);
}

// Round 13
// 74.855 us; speedup vs baseline: 1.1571x; 1.1571x over previous
//
#include <hip/hip_runtime.h>
#include <hip/hip_bf16.h>

// Shapes (fixed by setup_inputs): B=32, L=2048, V=30522, Dw=300, H=768, S=L/P=128
#define B_   32
#define L_   2048
#define V_   30522
#define DW   300
#define H_   768
#define KP   320              // Dw padded to multiple of 32 for MFMA K
#define NT   (H_/16)          // 48 n-tiles
#define KT   (KP/32)          // 10 k-tiles
#define VPAD 30528            // V rounded up; 30528 = 477 * 64 exactly
#define MB   64               // rows per block (4 m-tiles) -> grid 477 = single round @2/CU
#define NMT  4                // m-tiles per wave
#define NW   6                // n-tiles per wave (8 waves x 6 = 48)
#define APAD 336              // padded LDS row stride (bf16): 672 B rows, 16B-aligned

typedef __attribute__((ext_vector_type(8))) short bf16x8;
typedef __attribute__((ext_vector_type(4))) float f32x4;

// ---------------- K0: fused setup — pack_w | pe_table | sep_scan (blockIdx-ranged) ------------
// pack_w: Wp[(kt*NT+n)*64+lane] = 8 bf16 of W[k0..k0+8)[col]; col=n*16+(lane&15), k0=kt*32+(lane>>4)*8
__global__ void setup(const float* __restrict__ W, __hip_bfloat16* __restrict__ Wp,
                      float* __restrict__ PE, int peBlocks, int S,
                      const int* __restrict__ sep, int* __restrict__ pos,
                      int* __restrict__ nsep) {
    __shared__ int cnt[256];
    int bid = blockIdx.x;
    if (bid < 120) {                                   // ---- pack_w: 120*256 = NT*KT*64
        int t = bid * 256 + threadIdx.x;
        int lane = t & 63;
        int f    = t >> 6;
        int n    = f % NT;
        int kt   = f / NT;
        int col  = n * 16 + (lane & 15);
        int k0   = kt * 32 + (lane >> 4) * 8;
        union { __hip_bfloat16 h[8]; int4 v; } u;
        #pragma unroll
        for (int j = 0; j < 8; ++j) {
            int k = k0 + j;
            float w = (k < DW) ? W[(size_t)k * H_ + col] : 0.f;
            u.h[j] = __float2bfloat16(w);
        }
        reinterpret_cast<int4*>(Wp)[t] = u.v;
    } else if (bid < 120 + peBlocks) {                 // ---- pe_table
        int t = (bid - 120) * 256 + threadIdx.x;
        if (t < S * H_) {
            int s = t / H_, n = t % H_;
            const float cexp = -9.210340371976184f / (float)H_;   // -ln(10000)/H
            float div = expf((float)(2 * (n >> 1)) * cexp);
            float ang = (float)s * div;
            PE[t] = (n & 1) ? cosf(ang) : sinf(ang);
        }
    } else {                                           // ---- sep_scan: one block per batch row
        int b = bid - 120 - peBlocks;
        const int* row = sep + (size_t)b * L_;
        int tid = threadIdx.x;
        int local[8]; int c = 0;
        #pragma unroll
        for (int i = 0; i < 8; ++i) { int v = row[tid * 8 + i]; local[i] = v; c += v; }
        cnt[tid] = c; __syncthreads();
        for (int ofs = 1; ofs < 256; ofs <<= 1) {      // Hillis-Steele inclusive scan
            int v = (tid >= ofs) ? cnt[tid - ofs] : 0;
            __syncthreads();
            cnt[tid] += v;
            __syncthreads();
        }
        int w = cnt[tid] - c;                          // exclusive prefix
        #pragma unroll
        for (int i = 0; i < 8; ++i)
            if (local[i]) { pos[(size_t)b * L_ + w] = tid * 8 + i; ++w; }
        if (tid == 255) nsep[b] = cnt[255];
    }
}

// ---------------- K0b: h1 table [VPAD][KP] bf16 = LN1(emb_table) (one wave per vocab row) -----
__global__ void embed_ln1(const float* __restrict__ emb, const float* __restrict__ g1,
                          const float* __restrict__ b1, __hip_bfloat16* __restrict__ h1) {
    int wave = (blockIdx.x * blockDim.x + threadIdx.x) >> 6;
    int lane = threadIdx.x & 63;
    if (wave >= VPAD) return;
    __hip_bfloat16* dst = h1 + (size_t)wave * KP;
    if (wave >= V_) {                                  // zero pad rows
        for (int k = lane; k < KP; k += 64) dst[k] = __float2bfloat16(0.f);
        return;
    }
    const float* row = emb + (size_t)wave * DW;
    float x[5]; float s = 0.f, ss = 0.f;
    #pragma unroll
    for (int i = 0; i < 5; ++i) {                      // 5*64 = 320 covers KP exactly
        int k = lane + i * 64;
        float v = (k < DW) ? row[k] : 0.f;
        x[i] = v; s += v; ss += v * v;
    }
    #pragma unroll
    for (int m = 32; m >= 1; m >>= 1) { s += __shfl_xor(s, m); ss += __shfl_xor(ss, m); }
    float mu   = s / (float)DW;
    float var  = ss / (float)DW - mu * mu;
    float rstd = rsqrtf(var + 1e-12f);
    #pragma unroll
    for (int i = 0; i < 5; ++i) {
        int k = lane + i * 64;
        float o = (k < DW) ? (g1[k] * ((x[i] - mu) * rstd) + b1[k]) : 0.f;
        dst[k] = __float2bfloat16(o);
    }
}

// ---------------- K1: G[v] = LN2(relu(h1[v] @ W + b)) — MB=64, r10 pipeline + setprio ---------
// Block = 64 rows, 8 waves (512 thr); wave w owns n-tiles [w*6, w*6+6) for ALL 64 rows.
// Depth-1 B prefetch (r10's best; r11 depth-3 regressed) + sched_barrier(0) pin + T5 setprio.
// B-reuse 4x per load; grid 477 -> one dispatch round at 2 blocks/CU (no tail).
// C/D layout (m89-verified): col = lane&15, row = (lane>>4)*4 + reg.
__global__ void __launch_bounds__(512, 2)
gemm_ln2(const __hip_bfloat16* __restrict__ h1, const __hip_bfloat16* __restrict__ Wp,
         const float* __restrict__ bias, const float* __restrict__ g2,
         const float* __restrict__ b2, __hip_bfloat16* __restrict__ G) {
    __shared__ __hip_bfloat16 sA[MB * APAD];           // 43,008 B
    __shared__ float sred[2][8][MB];                   // 4 KB
    int tid  = threadIdx.x;
    int w    = tid >> 6;
    int lane = tid & 63;
    int r = lane & 15, q = lane >> 4;
    size_t row0 = (size_t)blockIdx.x * MB;

    // ---- stage A: 64 rows x 320 bf16 (40,960 B contiguous in h1) -> padded LDS ----
    const int4* gsrc = reinterpret_cast<const int4*>(h1 + row0 * KP);
    #pragma unroll
    for (int i = 0; i < 5; ++i) {
        int t4 = tid + i * 512;                        // int4 index, [0, 2560) exact
        int row = t4 / 40;                             // 40 int4 per row
        int col = (t4 % 40) * 8;
        *reinterpret_cast<int4*>(&sA[row * APAD + col]) = gsrc[t4];
    }

    f32x4 acc[NW][NMT];
    #pragma unroll
    for (int nl = 0; nl < NW; ++nl)
        #pragma unroll
        for (int m = 0; m < NMT; ++m) acc[nl][m] = (f32x4){0.f, 0.f, 0.f, 0.f};

    const bf16x8* Bv = reinterpret_cast<const bf16x8*>(Wp) + (size_t)w * NW * 64 + lane;
    const char* sAc = reinterpret_cast<const char*>(sA);
    const int abase = r * (APAD * 2) + q * 16;         // lane's A byte base (m=0, kt=0)
    int phase = (int)(blockIdx.x % KT);

    bf16x8 bbuf[2][NW];
    bf16x8 abuf[2][NMT];

    // prologue: issue B for kt=phase (independent of LDS), then barrier for sA
    {
        const bf16x8* bp = Bv + (size_t)phase * NT * 64;
        #pragma unroll
        for (int nl = 0; nl < NW; ++nl) bbuf[0][nl] = bp[nl * 64];
    }
    __syncthreads();                                   // sA ready
    #pragma unroll
    for (int m = 0; m < NMT; ++m)
        abuf[0][m] = *reinterpret_cast<const bf16x8*>(
            sAc + abase + m * (16 * APAD * 2) + phase * 64);

    #pragma unroll                                     // FULL unroll: all buf indices static
    for (int i = 0; i < KT; ++i) {
        const int cur = i & 1, nxt = (i + 1) & 1;
        if (i + 1 < KT) {                              // prefetch kt+1 (B global + A LDS)
            int ktn = phase + i + 1; if (ktn >= KT) ktn -= KT;
            const bf16x8* bp = Bv + (size_t)ktn * NT * 64;
            #pragma unroll
            for (int nl = 0; nl < NW; ++nl) bbuf[nxt][nl] = bp[nl * 64];
            #pragma unroll
            for (int m = 0; m < NMT; ++m)
                abuf[nxt][m] = *reinterpret_cast<const bf16x8*>(
                    sAc + abase + m * (16 * APAD * 2) + ktn * 64);
        }
        __builtin_amdgcn_sched_barrier(0);             // prefetch may NOT sink below MFMAs
        __builtin_amdgcn_s_setprio(1);                 // T5: favor MFMA wave (no-barrier loop)
        #pragma unroll
        for (int nl = 0; nl < NW; ++nl) {
            acc[nl][0] = __builtin_amdgcn_mfma_f32_16x16x32_bf16(abuf[cur][0], bbuf[cur][nl], acc[nl][0], 0, 0, 0);
            acc[nl][1] = __builtin_amdgcn_mfma_f32_16x16x32_bf16(abuf[cur][1], bbuf[cur][nl], acc[nl][1], 0, 0, 0);
            acc[nl][2] = __builtin_amdgcn_mfma_f32_16x16x32_bf16(abuf[cur][2], bbuf[cur][nl], acc[nl][2], 0, 0, 0);
            acc[nl][3] = __builtin_amdgcn_mfma_f32_16x16x32_bf16(abuf[cur][3], bbuf[cur][nl], acc[nl][3], 0, 0, 0);
        }
        __builtin_amdgcn_s_setprio(0);
    }

    // bias + relu + in-wave partial stats (over this wave's 96 cols)
    float s_[NMT][4], ss_[NMT][4];
    #pragma unroll
    for (int m = 0; m < NMT; ++m)
        #pragma unroll
        for (int j = 0; j < 4; ++j) { s_[m][j] = 0.f; ss_[m][j] = 0.f; }
    #pragma unroll
    for (int nl = 0; nl < NW; ++nl) {
        float bn = bias[w * 96 + nl * 16 + r];
        #pragma unroll
        for (int m = 0; m < NMT; ++m)
            #pragma unroll
            for (int j = 0; j < 4; ++j) {
                float v = acc[nl][m][j] + bn;
                v = v > 0.f ? v : 0.f;
                acc[nl][m][j] = v;
                s_[m][j] += v; ss_[m][j] += v * v;
            }
    }
    #pragma unroll
    for (int msk = 1; msk < 16; msk <<= 1)             // reduce across the 16 r-lanes
        #pragma unroll
        for (int m = 0; m < NMT; ++m)
            #pragma unroll
            for (int j = 0; j < 4; ++j) {
                s_[m][j]  += __shfl_xor(s_[m][j],  msk);
                ss_[m][j] += __shfl_xor(ss_[m][j], msk);
            }
    if (r == 0) {                                      // publish wave partials
        #pragma unroll
        for (int m = 0; m < NMT; ++m)
            #pragma unroll
            for (int j = 0; j < 4; ++j) {
                int row = m * 16 + q * 4 + j;
                sred[0][w][row] = s_[m][j];
                sred[1][w][row] = ss_[m][j];
            }
    }
    __syncthreads();

    #pragma unroll
    for (int m = 0; m < NMT; ++m) {
        #pragma unroll
        for (int j = 0; j < 4; ++j) {
            int row = m * 16 + q * 4 + j;
            float ts = 0.f, tss = 0.f;
            #pragma unroll
            for (int ww = 0; ww < 8; ++ww) { ts += sred[0][ww][row]; tss += sred[1][ww][row]; }
            float mu   = ts / (float)H_;
            float var  = tss / (float)H_ - mu * mu;
            float rstd = rsqrtf(var + 1e-12f);
            s_[m][j]  = mu;                            // reuse as mu
            ss_[m][j] = rstd;                          // reuse as rstd
        }
    }
    #pragma unroll
    for (int nl = 0; nl < NW; ++nl) {
        int col = w * 96 + nl * 16 + r;
        float gg = g2[col], bb = b2[col];
        #pragma unroll
        for (int m = 0; m < NMT; ++m)
            #pragma unroll
            for (int j = 0; j < 4; ++j) {
                size_t rowg = row0 + m * 16 + q * 4 + j;
                float val = gg * (acc[nl][m][j] - s_[m][j]) * ss_[m][j] + bb;
                G[rowg * H_ + col] = __float2bfloat16(val);
            }
    }
}

// ---------------- K2: out[b,s,:] = mean_{t in seg(b,s)} G[ids[b,t]] + PE[s] -------------------
// 384 thr = 4 groups x 96 lanes; group g sums tokens t = lo+g, lo+g+4, ... with int4
// (16B/lane = 8 bf16) gathers; LDS tree-combine 4->1; PE from precomputed table.
// NOTE r12 bug: branchless tid->g map was wrong for tid in [128,192) (g=2 instead of 1,
// negative l, OOB reads -> absmax 1.23). Plain div/mod is correct and costs ~4 VALU once.
__global__ void seg_gather(const int* __restrict__ ids, const int* __restrict__ pos,
                           const int* __restrict__ nsep, const __hip_bfloat16* __restrict__ G,
                           const float* __restrict__ PE, float* __restrict__ out, int S) {
    int blk = blockIdx.x;
    int s = blk % S, b = blk / S;
    int tid = threadIdx.x;
    int g = tid / 96;
    int l = tid % 96;
    int ns = nsep[b];
    int lo, hi;
    if (s > ns) { lo = 1; hi = 0; }                    // empty segment
    else {
        lo = (s == 0) ? 0 : pos[(size_t)b * L_ + (s - 1)] + 1;
        hi = (s < ns) ? pos[(size_t)b * L_ + s] - 1 : L_ - 1;   // s==ns: tail after last sep
    }
    int cnt = hi - lo + 1; if (cnt < 0) cnt = 0;

    float a[8] = {0.f, 0.f, 0.f, 0.f, 0.f, 0.f, 0.f, 0.f};
    for (int t = lo + g; t <= hi; t += 4) {
        int v = ids[(size_t)b * L_ + t];
        int4 raw = *reinterpret_cast<const int4*>(G + (size_t)v * H_ + l * 8);
        const unsigned short* u = reinterpret_cast<const unsigned short*>(&raw);
        #pragma unroll
        for (int k = 0; k < 8; ++k) {
            union { unsigned int i; float f; } c; c.i = ((unsigned int)u[k]) << 16;
            a[k] += c.f;
        }
    }
    __shared__ float red[3][96 * 8];                   // 9 KB
    if (g > 0) {
        #pragma unroll
        for (int k = 0; k < 8; ++k) red[g - 1][l * 8 + k] = a[k];
    }
    __syncthreads();
    if (g == 0) {
        float inv = (cnt > 0) ? 1.f / (float)cnt : 0.f;
        float* orow = out + ((size_t)b * S + s) * H_;
        const float* pe = PE + (size_t)s * H_;
        #pragma unroll
        for (int k = 0; k < 8; ++k) {
            int n = l * 8 + k;
            float tot = a[k] + red[0][l * 8 + k] + red[1][l * 8 + k] + red[2][l * 8 + k];
            orow[n] = tot * inv + pe[n];
        }
    }
}

// ---------------- host launcher ----------------
extern "C" void kernel_launch(void* const* d_in, const int* in_sizes, int n_in,
                              void* d_out, int out_size, void* d_ws, size_t ws_size,
                              hipStream_t stream) {
    const int*   ids  = (const int*)d_in[0];
    const int*   sep  = (const int*)d_in[1];
    const float* emb  = (const float*)d_in[3];
    const float* g1   = (const float*)d_in[4];
    const float* b1   = (const float*)d_in[5];
    const float* W    = (const float*)d_in[6];
    const float* bias = (const float*)d_in[7];
    const float* g2   = (const float*)d_in[8];
    const float* b2   = (const float*)d_in[9];
    float* out = (float*)d_out;

    int S = out_size / (B_ * H_);                      // 128

    // workspace layout (all offsets 16B-aligned)
    char* ws = (char*)d_ws;
    __hip_bfloat16* Wp  = (__hip_bfloat16*)(ws);                         // 491,520 B
    __hip_bfloat16* h1  = (__hip_bfloat16*)(ws + 491520);                // 19,537,920 B
    __hip_bfloat16* G   = (__hip_bfloat16*)(ws + 491520 + 19537920);     // 46,891,008 B
    int*   pos  = (int*)(ws + 491520 + 19537920 + 46891008);             // 262,144 B
    int*   nsep = (int*)(ws + 491520 + 19537920 + 46891008 + 262144);    // 256 B
    float* PE   = (float*)(ws + 491520 + 19537920 + 46891008 + 262144 + 256); // 393,216 B
    (void)ws_size; (void)n_in; (void)in_sizes;

    int peBlocks = (S * H_ + 255) / 256;               // 384 for S=128
    setup    <<<120 + peBlocks + B_, 256, 0, stream>>>(W, Wp, PE, peBlocks, S, sep, pos, nsep);
    embed_ln1<<<VPAD / 4, 256, 0, stream>>>(emb, g1, b1, h1);
    gemm_ln2 <<<VPAD / MB, 512, 0, stream>>>(h1, Wp, bias, g2, b2, G);
    seg_gather<<<B_ * S, 384, 0, stream>>>(ids, pos, nsep, G, PE, out, S);
}

// Round 14
// 72.490 us; speedup vs baseline: 1.1949x; 1.0326x over previous
//
#include <hip/hip_runtime.h>
#include <hip/hip_bf16.h>

// Shapes (fixed by setup_inputs): B=32, L=2048, V=30522, Dw=300, H=768, S=L/P=128
#define B_   32
#define L_   2048
#define V_   30522
#define DW   300
#define H_   768
#define KP   320              // Dw padded to multiple of 32 for MFMA K
#define NT   (H_/16)          // 48 n-tiles
#define KT   (KP/32)          // 10 k-tiles
#define VPAD 30528            // V rounded up; 30528 = 477 * 64 exactly
#define MB   64               // rows per block (4 m-tiles) -> grid 477 = single round @2/CU
#define NMT  4                // m-tiles per wave
#define NW   6                // n-tiles per wave (8 waves x 6 = 48)
#define APAD 336              // padded LDS row stride (bf16): 672 B rows, 16B-aligned

typedef __attribute__((ext_vector_type(8))) short bf16x8;
typedef __attribute__((ext_vector_type(4))) float f32x4;

// ---------------- K0: fused setup — pack_w | pe_table | sep_scan (blockIdx-ranged) ------------
// pack_w: Wp[(kt*NT+n)*64+lane] = 8 bf16 of W[k0..k0+8)[col]; col=n*16+(lane&15), k0=kt*32+(lane>>4)*8
__global__ void setup(const float* __restrict__ W, __hip_bfloat16* __restrict__ Wp,
                      float* __restrict__ PE, int peBlocks, int S,
                      const int* __restrict__ sep, int* __restrict__ pos,
                      int* __restrict__ nsep) {
    __shared__ int cnt[256];
    int bid = blockIdx.x;
    if (bid < 120) {                                   // ---- pack_w: 120*256 = NT*KT*64
        int t = bid * 256 + threadIdx.x;
        int lane = t & 63;
        int f    = t >> 6;
        int n    = f % NT;
        int kt   = f / NT;
        int col  = n * 16 + (lane & 15);
        int k0   = kt * 32 + (lane >> 4) * 8;
        union { __hip_bfloat16 h[8]; int4 v; } u;
        #pragma unroll
        for (int j = 0; j < 8; ++j) {
            int k = k0 + j;
            float w = (k < DW) ? W[(size_t)k * H_ + col] : 0.f;
            u.h[j] = __float2bfloat16(w);
        }
        reinterpret_cast<int4*>(Wp)[t] = u.v;
    } else if (bid < 120 + peBlocks) {                 // ---- pe_table
        int t = (bid - 120) * 256 + threadIdx.x;
        if (t < S * H_) {
            int s = t / H_, n = t % H_;
            const float cexp = -9.210340371976184f / (float)H_;   // -ln(10000)/H
            float div = expf((float)(2 * (n >> 1)) * cexp);
            float ang = (float)s * div;
            PE[t] = (n & 1) ? cosf(ang) : sinf(ang);
        }
    } else {                                           // ---- sep_scan: one block per batch row
        int b = bid - 120 - peBlocks;
        const int* row = sep + (size_t)b * L_;
        int tid = threadIdx.x;
        int local[8]; int c = 0;
        #pragma unroll
        for (int i = 0; i < 8; ++i) { int v = row[tid * 8 + i]; local[i] = v; c += v; }
        cnt[tid] = c; __syncthreads();
        for (int ofs = 1; ofs < 256; ofs <<= 1) {      // Hillis-Steele inclusive scan
            int v = (tid >= ofs) ? cnt[tid - ofs] : 0;
            __syncthreads();
            cnt[tid] += v;
            __syncthreads();
        }
        int w = cnt[tid] - c;                          // exclusive prefix
        #pragma unroll
        for (int i = 0; i < 8; ++i)
            if (local[i]) { pos[(size_t)b * L_ + w] = tid * 8 + i; ++w; }
        if (tid == 255) nsep[b] = cnt[255];
    }
}

// ---------------- K1: G[v] = LN2(relu(LN1(emb[v]) @ W + b)) — LN1 fused into A-staging --------
// Block = 64 rows, 8 waves (512 thr); wave w owns n-tiles [w*6, w*6+6) for ALL 64 rows.
// Staging: wave w computes LN1 for rows w*8..w*8+7 directly from emb (fp32, coalesced) into
// sA (bf16, APAD-padded) — deletes the separate embed_ln1 kernel and the h1 HBM round-trip.
// K-loop: depth-1 B prefetch + sched_barrier(0) pin + T5 setprio (r13's best, 41 us / 366 TF).
// C/D layout (m89-verified): col = lane&15, row = (lane>>4)*4 + reg.
__global__ void __launch_bounds__(512, 2)
gemm_ln2(const float* __restrict__ emb, const float* __restrict__ g1,
         const float* __restrict__ b1, const __hip_bfloat16* __restrict__ Wp,
         const float* __restrict__ bias, const float* __restrict__ g2,
         const float* __restrict__ b2, __hip_bfloat16* __restrict__ G) {
    __shared__ __hip_bfloat16 sA[MB * APAD];           // 43,008 B
    __shared__ float sred[2][8][MB];                   // 4 KB
    int tid  = threadIdx.x;
    int w    = tid >> 6;
    int lane = tid & 63;
    int r = lane & 15, q = lane >> 4;
    size_t row0 = (size_t)blockIdx.x * MB;

    const bf16x8* Bv = reinterpret_cast<const bf16x8*>(Wp) + (size_t)w * NW * 64 + lane;
    int phase = (int)(blockIdx.x % KT);

    bf16x8 bbuf[2][NW];
    bf16x8 abuf[2][NMT];

    // prologue: issue B loads for kt=phase FIRST (they overlap the LN1 staging compute)
    {
        const bf16x8* bp = Bv + (size_t)phase * NT * 64;
        #pragma unroll
        for (int nl = 0; nl < NW; ++nl) bbuf[0][nl] = bp[nl * 64];
    }

    // ---- fused LN1 staging: wave w handles rows w*8..w*8+7 (one row across 64 lanes) ----
    {
        float g1v[5], b1v[5];
        #pragma unroll
        for (int i = 0; i < 5; ++i) {
            int k = lane + i * 64;
            g1v[i] = (k < DW) ? g1[k] : 0.f;
            b1v[i] = (k < DW) ? b1[k] : 0.f;
        }
        #pragma unroll
        for (int rr = 0; rr < 8; ++rr) {
            int lrow = w * 8 + rr;                     // 0..63
            size_t gvr = row0 + lrow;
            __hip_bfloat16* dst = &sA[lrow * APAD];
            if (gvr < V_) {
                const float* rowp = emb + gvr * (size_t)DW;
                float x[5]; float s = 0.f, ssum = 0.f;
                #pragma unroll
                for (int i = 0; i < 5; ++i) {
                    int k = lane + i * 64;
                    float v = (k < DW) ? rowp[k] : 0.f;
                    x[i] = v; s += v; ssum += v * v;
                }
                #pragma unroll
                for (int m = 32; m >= 1; m >>= 1) { s += __shfl_xor(s, m); ssum += __shfl_xor(ssum, m); }
                float mu   = s / (float)DW;
                float var  = ssum / (float)DW - mu * mu;
                float rstd = rsqrtf(var + 1e-12f);
                #pragma unroll
                for (int i = 0; i < 5; ++i) {
                    int k = lane + i * 64;
                    float o = (k < DW) ? (g1v[i] * ((x[i] - mu) * rstd) + b1v[i]) : 0.f;
                    dst[k] = __float2bfloat16(o);
                }
            } else {                                   // pad rows 30522..30527 -> zeros
                for (int k = lane; k < KP; k += 64) dst[k] = __float2bfloat16(0.f);
            }
        }
    }

    f32x4 acc[NW][NMT];
    #pragma unroll
    for (int nl = 0; nl < NW; ++nl)
        #pragma unroll
        for (int m = 0; m < NMT; ++m) acc[nl][m] = (f32x4){0.f, 0.f, 0.f, 0.f};

    const char* sAc = reinterpret_cast<const char*>(sA);
    const int abase = r * (APAD * 2) + q * 16;         // lane's A byte base (m=0, kt=0)

    __syncthreads();                                   // sA ready
    #pragma unroll
    for (int m = 0; m < NMT; ++m)
        abuf[0][m] = *reinterpret_cast<const bf16x8*>(
            sAc + abase + m * (16 * APAD * 2) + phase * 64);

    #pragma unroll                                     // FULL unroll: all buf indices static
    for (int i = 0; i < KT; ++i) {
        const int cur = i & 1, nxt = (i + 1) & 1;
        if (i + 1 < KT) {                              // prefetch kt+1 (B global + A LDS)
            int ktn = phase + i + 1; if (ktn >= KT) ktn -= KT;
            const bf16x8* bp = Bv + (size_t)ktn * NT * 64;
            #pragma unroll
            for (int nl = 0; nl < NW; ++nl) bbuf[nxt][nl] = bp[nl * 64];
            #pragma unroll
            for (int m = 0; m < NMT; ++m)
                abuf[nxt][m] = *reinterpret_cast<const bf16x8*>(
                    sAc + abase + m * (16 * APAD * 2) + ktn * 64);
        }
        __builtin_amdgcn_sched_barrier(0);             // prefetch may NOT sink below MFMAs
        __builtin_amdgcn_s_setprio(1);                 // T5: favor MFMA wave (no-barrier loop)
        #pragma unroll
        for (int nl = 0; nl < NW; ++nl) {
            acc[nl][0] = __builtin_amdgcn_mfma_f32_16x16x32_bf16(abuf[cur][0], bbuf[cur][nl], acc[nl][0], 0, 0, 0);
            acc[nl][1] = __builtin_amdgcn_mfma_f32_16x16x32_bf16(abuf[cur][1], bbuf[cur][nl], acc[nl][1], 0, 0, 0);
            acc[nl][2] = __builtin_amdgcn_mfma_f32_16x16x32_bf16(abuf[cur][2], bbuf[cur][nl], acc[nl][2], 0, 0, 0);
            acc[nl][3] = __builtin_amdgcn_mfma_f32_16x16x32_bf16(abuf[cur][3], bbuf[cur][nl], acc[nl][3], 0, 0, 0);
        }
        __builtin_amdgcn_s_setprio(0);
    }

    // bias + relu + in-wave partial stats (over this wave's 96 cols)
    float s_[NMT][4], ss_[NMT][4];
    #pragma unroll
    for (int m = 0; m < NMT; ++m)
        #pragma unroll
        for (int j = 0; j < 4; ++j) { s_[m][j] = 0.f; ss_[m][j] = 0.f; }
    #pragma unroll
    for (int nl = 0; nl < NW; ++nl) {
        float bn = bias[w * 96 + nl * 16 + r];
        #pragma unroll
        for (int m = 0; m < NMT; ++m)
            #pragma unroll
            for (int j = 0; j < 4; ++j) {
                float v = acc[nl][m][j] + bn;
                v = v > 0.f ? v : 0.f;
                acc[nl][m][j] = v;
                s_[m][j] += v; ss_[m][j] += v * v;
            }
    }
    #pragma unroll
    for (int msk = 1; msk < 16; msk <<= 1)             // reduce across the 16 r-lanes
        #pragma unroll
        for (int m = 0; m < NMT; ++m)
            #pragma unroll
            for (int j = 0; j < 4; ++j) {
                s_[m][j]  += __shfl_xor(s_[m][j],  msk);
                ss_[m][j] += __shfl_xor(ss_[m][j], msk);
            }
    if (r == 0) {                                      // publish wave partials
        #pragma unroll
        for (int m = 0; m < NMT; ++m)
            #pragma unroll
            for (int j = 0; j < 4; ++j) {
                int row = m * 16 + q * 4 + j;
                sred[0][w][row] = s_[m][j];
                sred[1][w][row] = ss_[m][j];
            }
    }
    __syncthreads();

    #pragma unroll
    for (int m = 0; m < NMT; ++m) {
        #pragma unroll
        for (int j = 0; j < 4; ++j) {
            int row = m * 16 + q * 4 + j;
            float ts = 0.f, tss = 0.f;
            #pragma unroll
            for (int ww = 0; ww < 8; ++ww) { ts += sred[0][ww][row]; tss += sred[1][ww][row]; }
            float mu   = ts / (float)H_;
            float var  = tss / (float)H_ - mu * mu;
            float rstd = rsqrtf(var + 1e-12f);
            s_[m][j]  = mu;                            // reuse as mu
            ss_[m][j] = rstd;                          // reuse as rstd
        }
    }
    #pragma unroll
    for (int nl = 0; nl < NW; ++nl) {
        int col = w * 96 + nl * 16 + r;
        float gg = g2[col], bb = b2[col];
        #pragma unroll
        for (int m = 0; m < NMT; ++m)
            #pragma unroll
            for (int j = 0; j < 4; ++j) {
                size_t rowg = row0 + m * 16 + q * 4 + j;
                float val = gg * (acc[nl][m][j] - s_[m][j]) * ss_[m][j] + bb;
                G[rowg * H_ + col] = __float2bfloat16(val);
            }
    }
}

// ---------------- K2: out[b,s,:] = mean_{t in seg(b,s)} G[ids[b,t]] + PE[s] -------------------
// 384 thr = 4 groups x 96 lanes; group g sums tokens t = lo+g, lo+g+4, ... with int4
// (16B/lane = 8 bf16) gathers; LDS tree-combine 4->1; PE from precomputed table.
__global__ void seg_gather(const int* __restrict__ ids, const int* __restrict__ pos,
                           const int* __restrict__ nsep, const __hip_bfloat16* __restrict__ G,
                           const float* __restrict__ PE, float* __restrict__ out, int S) {
    int blk = blockIdx.x;
    int s = blk % S, b = blk / S;
    int tid = threadIdx.x;
    int g = tid / 96;
    int l = tid % 96;
    int ns = nsep[b];
    int lo, hi;
    if (s > ns) { lo = 1; hi = 0; }                    // empty segment
    else {
        lo = (s == 0) ? 0 : pos[(size_t)b * L_ + (s - 1)] + 1;
        hi = (s < ns) ? pos[(size_t)b * L_ + s] - 1 : L_ - 1;   // s==ns: tail after last sep
    }
    int cnt = hi - lo + 1; if (cnt < 0) cnt = 0;

    float a[8] = {0.f, 0.f, 0.f, 0.f, 0.f, 0.f, 0.f, 0.f};
    for (int t = lo + g; t <= hi; t += 4) {
        int v = ids[(size_t)b * L_ + t];
        int4 raw = *reinterpret_cast<const int4*>(G + (size_t)v * H_ + l * 8);
        const unsigned short* u = reinterpret_cast<const unsigned short*>(&raw);
        #pragma unroll
        for (int k = 0; k < 8; ++k) {
            union { unsigned int i; float f; } c; c.i = ((unsigned int)u[k]) << 16;
            a[k] += c.f;
        }
    }
    __shared__ float red[3][96 * 8];                   // 9 KB
    if (g > 0) {
        #pragma unroll
        for (int k = 0; k < 8; ++k) red[g - 1][l * 8 + k] = a[k];
    }
    __syncthreads();
    if (g == 0) {
        float inv = (cnt > 0) ? 1.f / (float)cnt : 0.f;
        float* orow = out + ((size_t)b * S + s) * H_;
        const float* pe = PE + (size_t)s * H_;
        #pragma unroll
        for (int k = 0; k < 8; ++k) {
            int n = l * 8 + k;
            float tot = a[k] + red[0][l * 8 + k] + red[1][l * 8 + k] + red[2][l * 8 + k];
            orow[n] = tot * inv + pe[n];
        }
    }
}

// ---------------- host launcher ----------------
extern "C" void kernel_launch(void* const* d_in, const int* in_sizes, int n_in,
                              void* d_out, int out_size, void* d_ws, size_t ws_size,
                              hipStream_t stream) {
    const int*   ids  = (const int*)d_in[0];
    const int*   sep  = (const int*)d_in[1];
    const float* emb  = (const float*)d_in[3];
    const float* g1   = (const float*)d_in[4];
    const float* b1   = (const float*)d_in[5];
    const float* W    = (const float*)d_in[6];
    const float* bias = (const float*)d_in[7];
    const float* g2   = (const float*)d_in[8];
    const float* b2   = (const float*)d_in[9];
    float* out = (float*)d_out;

    int S = out_size / (B_ * H_);                      // 128

    // workspace layout (all offsets 16B-aligned)
    char* ws = (char*)d_ws;
    __hip_bfloat16* Wp  = (__hip_bfloat16*)(ws);                         // 491,520 B
    __hip_bfloat16* G   = (__hip_bfloat16*)(ws + 491520);                // 46,891,008 B
    int*   pos  = (int*)(ws + 491520 + 46891008);                        // 262,144 B
    int*   nsep = (int*)(ws + 491520 + 46891008 + 262144);               // 256 B
    float* PE   = (float*)(ws + 491520 + 46891008 + 262144 + 256);       // 393,216 B
    (void)ws_size; (void)n_in; (void)in_sizes;

    int peBlocks = (S * H_ + 255) / 256;               // 384 for S=128
    setup    <<<120 + peBlocks + B_, 256, 0, stream>>>(W, Wp, PE, peBlocks, S, sep, pos, nsep);
    gemm_ln2 <<<VPAD / MB, 512, 0, stream>>>(emb, g1, b1, Wp, bias, g2, b2, G);
    seg_gather<<<B_ * S, 384, 0, stream>>>(ids, pos, nsep, G, PE, out, S);
}

// Round 15
// 71.824 us; speedup vs baseline: 1.2059x; 1.0093x over previous
//
#include <hip/hip_runtime.h>
#include <hip/hip_bf16.h>

// Shapes (fixed by setup_inputs): B=32, L=2048, V=30522, Dw=300, H=768, S=L/P=128
#define B_   32
#define L_   2048
#define V_   30522
#define DW   300
#define H_   768
#define KP   320              // Dw padded to multiple of 32 for MFMA K
#define NT   (H_/16)          // 48 n-tiles
#define KT   (KP/32)          // 10 k-tiles
#define VPAD 30528            // V rounded up; 30528 = 477 * 64 exactly
#define MB   64               // rows per block (4 m-tiles) -> grid 477 = single round @2/CU
#define NMT  4                // m-tiles per wave
#define NW   6                // n-tiles per wave (8 waves x 6 = 48)
#define APAD 336              // padded LDS row stride (bf16): 672 B rows, 16B-aligned

typedef __attribute__((ext_vector_type(8))) short bf16x8;
typedef __attribute__((ext_vector_type(4))) float f32x4;

// ---------------- K0: fused setup — pack_w | pe_table | sep_scan (blockIdx-ranged) ------------
// pack_w: Wp[(kt*NT+n)*64+lane] = 8 bf16 of W[k0..k0+8)[col]; col=n*16+(lane&15), k0=kt*32+(lane>>4)*8
__global__ void setup(const float* __restrict__ W, __hip_bfloat16* __restrict__ Wp,
                      float* __restrict__ PE, int peBlocks, int S,
                      const int* __restrict__ sep, int* __restrict__ pos,
                      int* __restrict__ nsep) {
    __shared__ int cnt[256];
    int bid = blockIdx.x;
    if (bid < 120) {                                   // ---- pack_w: 120*256 = NT*KT*64
        int t = bid * 256 + threadIdx.x;
        int lane = t & 63;
        int f    = t >> 6;
        int n    = f % NT;
        int kt   = f / NT;
        int col  = n * 16 + (lane & 15);
        int k0   = kt * 32 + (lane >> 4) * 8;
        union { __hip_bfloat16 h[8]; int4 v; } u;
        #pragma unroll
        for (int j = 0; j < 8; ++j) {
            int k = k0 + j;
            float w = (k < DW) ? W[(size_t)k * H_ + col] : 0.f;
            u.h[j] = __float2bfloat16(w);
        }
        reinterpret_cast<int4*>(Wp)[t] = u.v;
    } else if (bid < 120 + peBlocks) {                 // ---- pe_table
        int t = (bid - 120) * 256 + threadIdx.x;
        if (t < S * H_) {
            int s = t / H_, n = t % H_;
            const float cexp = -9.210340371976184f / (float)H_;   // -ln(10000)/H
            float div = expf((float)(2 * (n >> 1)) * cexp);
            float ang = (float)s * div;
            PE[t] = (n & 1) ? cosf(ang) : sinf(ang);
        }
    } else {                                           // ---- sep_scan: one block per batch row
        int b = bid - 120 - peBlocks;
        const int* row = sep + (size_t)b * L_;
        int tid = threadIdx.x;
        int local[8]; int c = 0;
        #pragma unroll
        for (int i = 0; i < 8; ++i) { int v = row[tid * 8 + i]; local[i] = v; c += v; }
        cnt[tid] = c; __syncthreads();
        for (int ofs = 1; ofs < 256; ofs <<= 1) {      // Hillis-Steele inclusive scan
            int v = (tid >= ofs) ? cnt[tid - ofs] : 0;
            __syncthreads();
            cnt[tid] += v;
            __syncthreads();
        }
        int w = cnt[tid] - c;                          // exclusive prefix
        #pragma unroll
        for (int i = 0; i < 8; ++i)
            if (local[i]) { pos[(size_t)b * L_ + w] = tid * 8 + i; ++w; }
        if (tid == 255) nsep[b] = cnt[255];
    }
}

// ---------------- K1: G[v] = LN2(relu(LN1(emb[v]) @ W + b)) — LN1 fused, 2-phase staging ------
// Block = 64 rows, 8 waves (512 thr); wave w owns n-tiles [w*6, w*6+6) for ALL 64 rows.
// Staging (r15 fix): phase 1 issues ALL 40 loads (8 rows x 5) into xx[8][5] back-to-back
// (one amortized HBM latency, T14 issue-early); phase 2 runs the 8 independent shfl-reduces.
// r14's per-row serial version exposed 8 HBM latencies (+14.5 us). Wave-uniform `full` flag
// hoists range checks (only block 476 takes the masked path).
// K-loop: depth-1 B prefetch + sched_barrier(0) pin + T5 setprio (r13's best).
// C/D layout (m89-verified): col = lane&15, row = (lane>>4)*4 + reg.
__global__ void __launch_bounds__(512, 2)
gemm_ln2(const float* __restrict__ emb, const float* __restrict__ g1,
         const float* __restrict__ b1, const __hip_bfloat16* __restrict__ Wp,
         const float* __restrict__ bias, const float* __restrict__ g2,
         const float* __restrict__ b2, __hip_bfloat16* __restrict__ G) {
    __shared__ __hip_bfloat16 sA[MB * APAD];           // 43,008 B
    __shared__ float sred[2][8][MB];                   // 4 KB
    int tid  = threadIdx.x;
    int w    = tid >> 6;
    int lane = tid & 63;
    int r = lane & 15, q = lane >> 4;
    size_t row0 = (size_t)blockIdx.x * MB;

    const bf16x8* Bv = reinterpret_cast<const bf16x8*>(Wp) + (size_t)w * NW * 64 + lane;
    int phase = (int)(blockIdx.x % KT);

    bf16x8 bbuf[2][NW];
    bf16x8 abuf[2][NMT];

    // prologue: issue B loads for kt=phase FIRST (they overlap the LN1 staging)
    {
        const bf16x8* bp = Bv + (size_t)phase * NT * 64;
        #pragma unroll
        for (int nl = 0; nl < NW; ++nl) bbuf[0][nl] = bp[nl * 64];
    }

    // ---- fused LN1 staging: wave w handles rows w*8..w*8+7; 2-phase (load-all, reduce-all) ---
    {
        float g1v[5], b1v[5];
        #pragma unroll
        for (int i = 0; i < 5; ++i) {
            int k = lane + i * 64;
            g1v[i] = (k < DW) ? g1[k] : 0.f;
            b1v[i] = (k < DW) ? b1[k] : 0.f;
        }
        bool full = (row0 + MB <= (size_t)V_);         // wave-uniform; false only for block 476
        if (full) {
            const float* base = emb + (row0 + (size_t)w * 8) * DW;
            float xx[8][5];
            #pragma unroll                             // phase 1: 40 loads in flight
            for (int rr = 0; rr < 8; ++rr)
                #pragma unroll
                for (int i = 0; i < 5; ++i) {
                    int k = lane + i * 64;
                    xx[rr][i] = (k < DW) ? base[rr * DW + k] : 0.f;
                }
            #pragma unroll                             // phase 2: 8 independent reduces
            for (int rr = 0; rr < 8; ++rr) {
                float s = 0.f, ssum = 0.f;
                #pragma unroll
                for (int i = 0; i < 5; ++i) { s += xx[rr][i]; ssum += xx[rr][i] * xx[rr][i]; }
                #pragma unroll
                for (int m = 32; m >= 1; m >>= 1) { s += __shfl_xor(s, m); ssum += __shfl_xor(ssum, m); }
                float mu   = s / (float)DW;
                float var  = ssum / (float)DW - mu * mu;
                float rstd = rsqrtf(var + 1e-12f);
                __hip_bfloat16* dst = &sA[(w * 8 + rr) * APAD];
                #pragma unroll
                for (int i = 0; i < 5; ++i) {
                    int k = lane + i * 64;
                    float o = (k < DW) ? (g1v[i] * ((xx[rr][i] - mu) * rstd) + b1v[i]) : 0.f;
                    dst[k] = __float2bfloat16(o);
                }
            }
        } else {                                       // last block: per-row masked path
            #pragma unroll
            for (int rr = 0; rr < 8; ++rr) {
                int lrow = w * 8 + rr;
                size_t gvr = row0 + lrow;
                __hip_bfloat16* dst = &sA[lrow * APAD];
                if (gvr < V_) {
                    const float* rowp = emb + gvr * (size_t)DW;
                    float x[5]; float s = 0.f, ssum = 0.f;
                    #pragma unroll
                    for (int i = 0; i < 5; ++i) {
                        int k = lane + i * 64;
                        float v = (k < DW) ? rowp[k] : 0.f;
                        x[i] = v; s += v; ssum += v * v;
                    }
                    #pragma unroll
                    for (int m = 32; m >= 1; m >>= 1) { s += __shfl_xor(s, m); ssum += __shfl_xor(ssum, m); }
                    float mu   = s / (float)DW;
                    float var  = ssum / (float)DW - mu * mu;
                    float rstd = rsqrtf(var + 1e-12f);
                    #pragma unroll
                    for (int i = 0; i < 5; ++i) {
                        int k = lane + i * 64;
                        float o = (k < DW) ? (g1v[i] * ((x[i] - mu) * rstd) + b1v[i]) : 0.f;
                        dst[k] = __float2bfloat16(o);
                    }
                } else {
                    for (int k = lane; k < KP; k += 64) dst[k] = __float2bfloat16(0.f);
                }
            }
        }
    }

    f32x4 acc[NW][NMT];
    #pragma unroll
    for (int nl = 0; nl < NW; ++nl)
        #pragma unroll
        for (int m = 0; m < NMT; ++m) acc[nl][m] = (f32x4){0.f, 0.f, 0.f, 0.f};

    const char* sAc = reinterpret_cast<const char*>(sA);
    const int abase = r * (APAD * 2) + q * 16;         // lane's A byte base (m=0, kt=0)

    __syncthreads();                                   // sA ready
    #pragma unroll
    for (int m = 0; m < NMT; ++m)
        abuf[0][m] = *reinterpret_cast<const bf16x8*>(
            sAc + abase + m * (16 * APAD * 2) + phase * 64);

    #pragma unroll                                     // FULL unroll: all buf indices static
    for (int i = 0; i < KT; ++i) {
        const int cur = i & 1, nxt = (i + 1) & 1;
        if (i + 1 < KT) {                              // prefetch kt+1 (B global + A LDS)
            int ktn = phase + i + 1; if (ktn >= KT) ktn -= KT;
            const bf16x8* bp = Bv + (size_t)ktn * NT * 64;
            #pragma unroll
            for (int nl = 0; nl < NW; ++nl) bbuf[nxt][nl] = bp[nl * 64];
            #pragma unroll
            for (int m = 0; m < NMT; ++m)
                abuf[nxt][m] = *reinterpret_cast<const bf16x8*>(
                    sAc + abase + m * (16 * APAD * 2) + ktn * 64);
        }
        __builtin_amdgcn_sched_barrier(0);             // prefetch may NOT sink below MFMAs
        __builtin_amdgcn_s_setprio(1);                 // T5: favor MFMA wave (no-barrier loop)
        #pragma unroll
        for (int nl = 0; nl < NW; ++nl) {
            acc[nl][0] = __builtin_amdgcn_mfma_f32_16x16x32_bf16(abuf[cur][0], bbuf[cur][nl], acc[nl][0], 0, 0, 0);
            acc[nl][1] = __builtin_amdgcn_mfma_f32_16x16x32_bf16(abuf[cur][1], bbuf[cur][nl], acc[nl][1], 0, 0, 0);
            acc[nl][2] = __builtin_amdgcn_mfma_f32_16x16x32_bf16(abuf[cur][2], bbuf[cur][nl], acc[nl][2], 0, 0, 0);
            acc[nl][3] = __builtin_amdgcn_mfma_f32_16x16x32_bf16(abuf[cur][3], bbuf[cur][nl], acc[nl][3], 0, 0, 0);
        }
        __builtin_amdgcn_s_setprio(0);
    }

    // bias + relu + in-wave partial stats (over this wave's 96 cols)
    float s_[NMT][4], ss_[NMT][4];
    #pragma unroll
    for (int m = 0; m < NMT; ++m)
        #pragma unroll
        for (int j = 0; j < 4; ++j) { s_[m][j] = 0.f; ss_[m][j] = 0.f; }
    #pragma unroll
    for (int nl = 0; nl < NW; ++nl) {
        float bn = bias[w * 96 + nl * 16 + r];
        #pragma unroll
        for (int m = 0; m < NMT; ++m)
            #pragma unroll
            for (int j = 0; j < 4; ++j) {
                float v = acc[nl][m][j] + bn;
                v = v > 0.f ? v : 0.f;
                acc[nl][m][j] = v;
                s_[m][j] += v; ss_[m][j] += v * v;
            }
    }
    #pragma unroll
    for (int msk = 1; msk < 16; msk <<= 1)             // reduce across the 16 r-lanes
        #pragma unroll
        for (int m = 0; m < NMT; ++m)
            #pragma unroll
            for (int j = 0; j < 4; ++j) {
                s_[m][j]  += __shfl_xor(s_[m][j],  msk);
                ss_[m][j] += __shfl_xor(ss_[m][j], msk);
            }
    if (r == 0) {                                      // publish wave partials
        #pragma unroll
        for (int m = 0; m < NMT; ++m)
            #pragma unroll
            for (int j = 0; j < 4; ++j) {
                int row = m * 16 + q * 4 + j;
                sred[0][w][row] = s_[m][j];
                sred[1][w][row] = ss_[m][j];
            }
    }
    __syncthreads();

    #pragma unroll
    for (int m = 0; m < NMT; ++m) {
        #pragma unroll
        for (int j = 0; j < 4; ++j) {
            int row = m * 16 + q * 4 + j;
            float ts = 0.f, tss = 0.f;
            #pragma unroll
            for (int ww = 0; ww < 8; ++ww) { ts += sred[0][ww][row]; tss += sred[1][ww][row]; }
            float mu   = ts / (float)H_;
            float var  = tss / (float)H_ - mu * mu;
            float rstd = rsqrtf(var + 1e-12f);
            s_[m][j]  = mu;                            // reuse as mu
            ss_[m][j] = rstd;                          // reuse as rstd
        }
    }
    #pragma unroll
    for (int nl = 0; nl < NW; ++nl) {
        int col = w * 96 + nl * 16 + r;
        float gg = g2[col], bb = b2[col];
        #pragma unroll
        for (int m = 0; m < NMT; ++m)
            #pragma unroll
            for (int j = 0; j < 4; ++j) {
                size_t rowg = row0 + m * 16 + q * 4 + j;
                float val = gg * (acc[nl][m][j] - s_[m][j]) * ss_[m][j] + bb;
                G[rowg * H_ + col] = __float2bfloat16(val);
            }
    }
}

// ---------------- K2: out[b,s,:] = mean_{t in seg(b,s)} G[ids[b,t]] + PE[s] -------------------
// 384 thr = 4 groups x 96 lanes; group g sums tokens t = lo+g, lo+g+4, ... with int4
// (16B/lane = 8 bf16) gathers; LDS tree-combine 4->1; PE from precomputed table.
__global__ void seg_gather(const int* __restrict__ ids, const int* __restrict__ pos,
                           const int* __restrict__ nsep, const __hip_bfloat16* __restrict__ G,
                           const float* __restrict__ PE, float* __restrict__ out, int S) {
    int blk = blockIdx.x;
    int s = blk % S, b = blk / S;
    int tid = threadIdx.x;
    int g = tid / 96;
    int l = tid % 96;
    int ns = nsep[b];
    int lo, hi;
    if (s > ns) { lo = 1; hi = 0; }                    // empty segment
    else {
        lo = (s == 0) ? 0 : pos[(size_t)b * L_ + (s - 1)] + 1;
        hi = (s < ns) ? pos[(size_t)b * L_ + s] - 1 : L_ - 1;   // s==ns: tail after last sep
    }
    int cnt = hi - lo + 1; if (cnt < 0) cnt = 0;

    float a[8] = {0.f, 0.f, 0.f, 0.f, 0.f, 0.f, 0.f, 0.f};
    for (int t = lo + g; t <= hi; t += 4) {
        int v = ids[(size_t)b * L_ + t];
        int4 raw = *reinterpret_cast<const int4*>(G + (size_t)v * H_ + l * 8);
        const unsigned short* u = reinterpret_cast<const unsigned short*>(&raw);
        #pragma unroll
        for (int k = 0; k < 8; ++k) {
            union { unsigned int i; float f; } c; c.i = ((unsigned int)u[k]) << 16;
            a[k] += c.f;
        }
    }
    __shared__ float red[3][96 * 8];                   // 9 KB
    if (g > 0) {
        #pragma unroll
        for (int k = 0; k < 8; ++k) red[g - 1][l * 8 + k] = a[k];
    }
    __syncthreads();
    if (g == 0) {
        float inv = (cnt > 0) ? 1.f / (float)cnt : 0.f;
        float* orow = out + ((size_t)b * S + s) * H_;
        const float* pe = PE + (size_t)s * H_;
        #pragma unroll
        for (int k = 0; k < 8; ++k) {
            int n = l * 8 + k;
            float tot = a[k] + red[0][l * 8 + k] + red[1][l * 8 + k] + red[2][l * 8 + k];
            orow[n] = tot * inv + pe[n];
        }
    }
}

// ---------------- host launcher ----------------
extern "C" void kernel_launch(void* const* d_in, const int* in_sizes, int n_in,
                              void* d_out, int out_size, void* d_ws, size_t ws_size,
                              hipStream_t stream) {
    const int*   ids  = (const int*)d_in[0];
    const int*   sep  = (const int*)d_in[1];
    const float* emb  = (const float*)d_in[3];
    const float* g1   = (const float*)d_in[4];
    const float* b1   = (const float*)d_in[5];
    const float* W    = (const float*)d_in[6];
    const float* bias = (const float*)d_in[7];
    const float* g2   = (const float*)d_in[8];
    const float* b2   = (const float*)d_in[9];
    float* out = (float*)d_out;

    int S = out_size / (B_ * H_);                      // 128

    // workspace layout (all offsets 16B-aligned)
    char* ws = (char*)d_ws;
    __hip_bfloat16* Wp  = (__hip_bfloat16*)(ws);                         // 491,520 B
    __hip_bfloat16* G   = (__hip_bfloat16*)(ws + 491520);                // 46,891,008 B
    int*   pos  = (int*)(ws + 491520 + 46891008);                        // 262,144 B
    int*   nsep = (int*)(ws + 491520 + 46891008 + 262144);               // 256 B
    float* PE   = (float*)(ws + 491520 + 46891008 + 262144 + 256);       // 393,216 B
    (void)ws_size; (void)n_in; (void)in_sizes;

    int peBlocks = (S * H_ + 255) / 256;               // 384 for S=128
    setup    <<<120 + peBlocks + B_, 256, 0, stream>>>(W, Wp, PE, peBlocks, S, sep, pos, nsep);
    gemm_ln2 <<<VPAD / MB, 512, 0, stream>>>(emb, g1, b1, Wp, bias, g2, b2, G);
    seg_gather<<<B_ * S, 384, 0, stream>>>(ids, pos, nsep, G, PE, out, S);
}

// Round 16
// 68.039 us; speedup vs baseline: 1.2730x; 1.0556x over previous
//
#include <hip/hip_runtime.h>
#include <hip/hip_bf16.h>

// Shapes (fixed by setup_inputs): B=32, L=2048, V=30522, Dw=300, H=768, S=L/P=128
#define B_   32
#define L_   2048
#define V_   30522
#define DW   300
#define H_   768
#define KP   320              // Dw padded to multiple of 32 for MFMA K
#define NT   (H_/16)          // 48 n-tiles
#define KT   (KP/32)          // 10 k-tiles
#define VPAD 30528            // V rounded up; 30528 = 954 * 32 exactly
#define MB   32               // rows per block (2 m-tiles) -> acc 48 AGPR, 2 blocks/CU
#define NMT  2                // m-tiles per wave
#define NW   6                // n-tiles per wave (8 waves x 6 = 48)
#define APAD 336              // padded LDS row stride (bf16): 672 B rows, 16B-aligned

typedef __attribute__((ext_vector_type(8))) short bf16x8;
typedef __attribute__((ext_vector_type(4))) float f32x4;

// ---------------- K0: fused setup — pack_w | pe_table | sep_scan (blockIdx-ranged) ------------
__global__ void setup(const float* __restrict__ W, __hip_bfloat16* __restrict__ Wp,
                      float* __restrict__ PE, int peBlocks, int S,
                      const int* __restrict__ sep, int* __restrict__ pos,
                      int* __restrict__ nsep) {
    __shared__ int cnt[256];
    int bid = blockIdx.x;
    if (bid < 120) {                                   // ---- pack_w: 120*256 = NT*KT*64
        int t = bid * 256 + threadIdx.x;
        int lane = t & 63;
        int f    = t >> 6;
        int n    = f % NT;
        int kt   = f / NT;
        int col  = n * 16 + (lane & 15);
        int k0   = kt * 32 + (lane >> 4) * 8;
        union { __hip_bfloat16 h[8]; int4 v; } u;
        #pragma unroll
        for (int j = 0; j < 8; ++j) {
            int k = k0 + j;
            float w = (k < DW) ? W[(size_t)k * H_ + col] : 0.f;
            u.h[j] = __float2bfloat16(w);
        }
        reinterpret_cast<int4*>(Wp)[t] = u.v;
    } else if (bid < 120 + peBlocks) {                 // ---- pe_table
        int t = (bid - 120) * 256 + threadIdx.x;
        if (t < S * H_) {
            int s = t / H_, n = t % H_;
            const float cexp = -9.210340371976184f / (float)H_;   // -ln(10000)/H
            float div = expf((float)(2 * (n >> 1)) * cexp);
            float ang = (float)s * div;
            PE[t] = (n & 1) ? cosf(ang) : sinf(ang);
        }
    } else {                                           // ---- sep_scan: one block per batch row
        int b = bid - 120 - peBlocks;
        const int* row = sep + (size_t)b * L_;
        int tid = threadIdx.x;
        int local[8]; int c = 0;
        #pragma unroll
        for (int i = 0; i < 8; ++i) { int v = row[tid * 8 + i]; local[i] = v; c += v; }
        cnt[tid] = c; __syncthreads();
        for (int ofs = 1; ofs < 256; ofs <<= 1) {      // Hillis-Steele inclusive scan
            int v = (tid >= ofs) ? cnt[tid - ofs] : 0;
            __syncthreads();
            cnt[tid] += v;
            __syncthreads();
        }
        int w = cnt[tid] - c;                          // exclusive prefix
        #pragma unroll
        for (int i = 0; i < 8; ++i)
            if (local[i]) { pos[(size_t)b * L_ + w] = tid * 8 + i; ++w; }
        if (tid == 255) nsep[b] = cnt[255];
    }
}

// ---------------- K1: G[v] = LN2(relu(LN1(emb[v]) @ W + b)) — MB=32, 2 blocks/CU --------------
// r16 occupancy fix: MB 64->32 halves acc (96->48 AGPR); no abuf prefetch (A direct from
// LDS, compiler's counted lgkmcnt); staging in 2-row batches (xx[2][5]). Live regs ~120
// under the launch_bounds(512,4) cap of 128 -> 4 waves/SIMD = 2 resident blocks/CU, so
// one block's HBM staging/epilogue overlaps the other's K-loop (m114). Grid 954, 1.86 rounds.
// K-loop: depth-1 B prefetch + sched_barrier(0) + setprio (r10/r13 winners).
// C/D layout (m89-verified): col = lane&15, row = (lane>>4)*4 + reg.
__global__ void __launch_bounds__(512, 4)
gemm_ln2(const float* __restrict__ emb, const float* __restrict__ g1,
         const float* __restrict__ b1, const __hip_bfloat16* __restrict__ Wp,
         const float* __restrict__ bias, const float* __restrict__ g2,
         const float* __restrict__ b2, __hip_bfloat16* __restrict__ G) {
    __shared__ __hip_bfloat16 sA[MB * APAD];           // 21,504 B
    __shared__ float sred[2][8][MB];                   // 2 KB
    int tid  = threadIdx.x;
    int w    = tid >> 6;
    int lane = tid & 63;
    int r = lane & 15, q = lane >> 4;
    size_t row0 = (size_t)blockIdx.x * MB;

    const bf16x8* Bv = reinterpret_cast<const bf16x8*>(Wp) + (size_t)w * NW * 64 + lane;
    int phase = (int)(blockIdx.x % KT);

    bf16x8 bbuf[2][NW];

    // prologue: issue B loads for kt=phase FIRST (they overlap the LN1 staging)
    {
        const bf16x8* bp = Bv + (size_t)phase * NT * 64;
        #pragma unroll
        for (int nl = 0; nl < NW; ++nl) bbuf[0][nl] = bp[nl * 64];
    }

    // ---- fused LN1 staging: wave w handles rows w*4..w*4+3, in 2 batches of 2 rows ----
    {
        float g1v[5], b1v[5];
        #pragma unroll
        for (int i = 0; i < 5; ++i) {
            int k = lane + i * 64;
            g1v[i] = (k < DW) ? g1[k] : 0.f;
            b1v[i] = (k < DW) ? b1[k] : 0.f;
        }
        bool full = (row0 + MB <= (size_t)V_);         // wave-uniform; false only last block
        if (full) {
            const float* base = emb + (row0 + (size_t)w * 4) * DW;
            #pragma unroll
            for (int batch = 0; batch < 2; ++batch) {
                float xx[2][5];
                #pragma unroll                         // issue 10 loads back-to-back
                for (int rr = 0; rr < 2; ++rr)
                    #pragma unroll
                    for (int i = 0; i < 5; ++i) {
                        int k = lane + i * 64;
                        xx[rr][i] = (k < DW) ? base[(batch * 2 + rr) * DW + k] : 0.f;
                    }
                #pragma unroll                         // 2 independent reduces
                for (int rr = 0; rr < 2; ++rr) {
                    float s = 0.f, ssum = 0.f;
                    #pragma unroll
                    for (int i = 0; i < 5; ++i) { s += xx[rr][i]; ssum += xx[rr][i] * xx[rr][i]; }
                    #pragma unroll
                    for (int m = 32; m >= 1; m >>= 1) { s += __shfl_xor(s, m); ssum += __shfl_xor(ssum, m); }
                    float mu   = s / (float)DW;
                    float var  = ssum / (float)DW - mu * mu;
                    float rstd = rsqrtf(var + 1e-12f);
                    __hip_bfloat16* dst = &sA[(w * 4 + batch * 2 + rr) * APAD];
                    #pragma unroll
                    for (int i = 0; i < 5; ++i) {
                        int k = lane + i * 64;
                        float o = (k < DW) ? (g1v[i] * ((xx[rr][i] - mu) * rstd) + b1v[i]) : 0.f;
                        dst[k] = __float2bfloat16(o);
                    }
                }
            }
        } else {                                       // last block: per-row masked path
            #pragma unroll
            for (int rr = 0; rr < 4; ++rr) {
                int lrow = w * 4 + rr;
                size_t gvr = row0 + lrow;
                __hip_bfloat16* dst = &sA[lrow * APAD];
                if (gvr < V_) {
                    const float* rowp = emb + gvr * (size_t)DW;
                    float x[5]; float s = 0.f, ssum = 0.f;
                    #pragma unroll
                    for (int i = 0; i < 5; ++i) {
                        int k = lane + i * 64;
                        float v = (k < DW) ? rowp[k] : 0.f;
                        x[i] = v; s += v; ssum += v * v;
                    }
                    #pragma unroll
                    for (int m = 32; m >= 1; m >>= 1) { s += __shfl_xor(s, m); ssum += __shfl_xor(ssum, m); }
                    float mu   = s / (float)DW;
                    float var  = ssum / (float)DW - mu * mu;
                    float rstd = rsqrtf(var + 1e-12f);
                    #pragma unroll
                    for (int i = 0; i < 5; ++i) {
                        int k = lane + i * 64;
                        float o = (k < DW) ? (g1v[i] * ((x[i] - mu) * rstd) + b1v[i]) : 0.f;
                        dst[k] = __float2bfloat16(o);
                    }
                } else {
                    for (int k = lane; k < KP; k += 64) dst[k] = __float2bfloat16(0.f);
                }
            }
        }
    }

    f32x4 acc[NW][NMT];
    #pragma unroll
    for (int nl = 0; nl < NW; ++nl)
        #pragma unroll
        for (int m = 0; m < NMT; ++m) acc[nl][m] = (f32x4){0.f, 0.f, 0.f, 0.f};

    const char* sAc = reinterpret_cast<const char*>(sA);
    const int abase = r * (APAD * 2) + q * 16;         // lane's A byte base (m=0, kt=0)

    __syncthreads();                                   // sA ready

    #pragma unroll                                     // FULL unroll: all buf indices static
    for (int i = 0; i < KT; ++i) {
        const int cur = i & 1, nxt = (i + 1) & 1;
        int kt = phase + i; if (kt >= KT) kt -= KT;
        if (i + 1 < KT) {                              // prefetch kt+1's B (global)
            int ktn = phase + i + 1; if (ktn >= KT) ktn -= KT;
            const bf16x8* bp = Bv + (size_t)ktn * NT * 64;
            #pragma unroll
            for (int nl = 0; nl < NW; ++nl) bbuf[nxt][nl] = bp[nl * 64];
        }
        __builtin_amdgcn_sched_barrier(0);             // prefetch may NOT sink below MFMAs
        // A direct from LDS (compiler emits counted lgkmcnt; saves abuf regs)
        bf16x8 a0 = *reinterpret_cast<const bf16x8*>(sAc + abase + kt * 64);
        bf16x8 a1 = *reinterpret_cast<const bf16x8*>(sAc + abase + 16 * APAD * 2 + kt * 64);
        __builtin_amdgcn_s_setprio(1);                 // T5: favor MFMA wave
        #pragma unroll
        for (int nl = 0; nl < NW; ++nl) {
            acc[nl][0] = __builtin_amdgcn_mfma_f32_16x16x32_bf16(a0, bbuf[cur][nl], acc[nl][0], 0, 0, 0);
            acc[nl][1] = __builtin_amdgcn_mfma_f32_16x16x32_bf16(a1, bbuf[cur][nl], acc[nl][1], 0, 0, 0);
        }
        __builtin_amdgcn_s_setprio(0);
    }

    // bias + relu + in-wave partial stats (over this wave's 96 cols)
    float s_[NMT][4], ss_[NMT][4];
    #pragma unroll
    for (int m = 0; m < NMT; ++m)
        #pragma unroll
        for (int j = 0; j < 4; ++j) { s_[m][j] = 0.f; ss_[m][j] = 0.f; }
    #pragma unroll
    for (int nl = 0; nl < NW; ++nl) {
        float bn = bias[w * 96 + nl * 16 + r];
        #pragma unroll
        for (int m = 0; m < NMT; ++m)
            #pragma unroll
            for (int j = 0; j < 4; ++j) {
                float v = acc[nl][m][j] + bn;
                v = v > 0.f ? v : 0.f;
                acc[nl][m][j] = v;
                s_[m][j] += v; ss_[m][j] += v * v;
            }
    }
    #pragma unroll
    for (int msk = 1; msk < 16; msk <<= 1)             // reduce across the 16 r-lanes
        #pragma unroll
        for (int m = 0; m < NMT; ++m)
            #pragma unroll
            for (int j = 0; j < 4; ++j) {
                s_[m][j]  += __shfl_xor(s_[m][j],  msk);
                ss_[m][j] += __shfl_xor(ss_[m][j], msk);
            }
    if (r == 0) {                                      // publish wave partials
        #pragma unroll
        for (int m = 0; m < NMT; ++m)
            #pragma unroll
            for (int j = 0; j < 4; ++j) {
                int row = m * 16 + q * 4 + j;
                sred[0][w][row] = s_[m][j];
                sred[1][w][row] = ss_[m][j];
            }
    }
    __syncthreads();

    #pragma unroll
    for (int m = 0; m < NMT; ++m) {
        #pragma unroll
        for (int j = 0; j < 4; ++j) {
            int row = m * 16 + q * 4 + j;
            float ts = 0.f, tss = 0.f;
            #pragma unroll
            for (int ww = 0; ww < 8; ++ww) { ts += sred[0][ww][row]; tss += sred[1][ww][row]; }
            float mu   = ts / (float)H_;
            float var  = tss / (float)H_ - mu * mu;
            float rstd = rsqrtf(var + 1e-12f);
            s_[m][j]  = mu;                            // reuse as mu
            ss_[m][j] = rstd;                          // reuse as rstd
        }
    }
    #pragma unroll
    for (int nl = 0; nl < NW; ++nl) {
        int col = w * 96 + nl * 16 + r;
        float gg = g2[col], bb = b2[col];
        #pragma unroll
        for (int m = 0; m < NMT; ++m)
            #pragma unroll
            for (int j = 0; j < 4; ++j) {
                size_t rowg = row0 + m * 16 + q * 4 + j;
                float val = gg * (acc[nl][m][j] - s_[m][j]) * ss_[m][j] + bb;
                G[rowg * H_ + col] = __float2bfloat16(val);
            }
    }
}

// ---------------- K2: out[b,s,:] = mean_{t in seg(b,s)} G[ids[b,t]] + PE[s] -------------------
// 384 thr = 4 groups x 96 lanes; group g sums tokens t = lo+g, lo+g+4, ... with int4
// (16B/lane = 8 bf16) gathers; LDS tree-combine 4->1; PE from precomputed table.
__global__ void seg_gather(const int* __restrict__ ids, const int* __restrict__ pos,
                           const int* __restrict__ nsep, const __hip_bfloat16* __restrict__ G,
                           const float* __restrict__ PE, float* __restrict__ out, int S) {
    int blk = blockIdx.x;
    int s = blk % S, b = blk / S;
    int tid = threadIdx.x;
    int g = tid / 96;
    int l = tid % 96;
    int ns = nsep[b];
    int lo, hi;
    if (s > ns) { lo = 1; hi = 0; }                    // empty segment
    else {
        lo = (s == 0) ? 0 : pos[(size_t)b * L_ + (s - 1)] + 1;
        hi = (s < ns) ? pos[(size_t)b * L_ + s] - 1 : L_ - 1;   // s==ns: tail after last sep
    }
    int cnt = hi - lo + 1; if (cnt < 0) cnt = 0;

    float a[8] = {0.f, 0.f, 0.f, 0.f, 0.f, 0.f, 0.f, 0.f};
    for (int t = lo + g; t <= hi; t += 4) {
        int v = ids[(size_t)b * L_ + t];
        int4 raw = *reinterpret_cast<const int4*>(G + (size_t)v * H_ + l * 8);
        const unsigned short* u = reinterpret_cast<const unsigned short*>(&raw);
        #pragma unroll
        for (int k = 0; k < 8; ++k) {
            union { unsigned int i; float f; } c; c.i = ((unsigned int)u[k]) << 16;
            a[k] += c.f;
        }
    }
    __shared__ float red[3][96 * 8];                   // 9 KB
    if (g > 0) {
        #pragma unroll
        for (int k = 0; k < 8; ++k) red[g - 1][l * 8 + k] = a[k];
    }
    __syncthreads();
    if (g == 0) {
        float inv = (cnt > 0) ? 1.f / (float)cnt : 0.f;
        float* orow = out + ((size_t)b * S + s) * H_;
        const float* pe = PE + (size_t)s * H_;
        #pragma unroll
        for (int k = 0; k < 8; ++k) {
            int n = l * 8 + k;
            float tot = a[k] + red[0][l * 8 + k] + red[1][l * 8 + k] + red[2][l * 8 + k];
            orow[n] = tot * inv + pe[n];
        }
    }
}

// ---------------- host launcher ----------------
extern "C" void kernel_launch(void* const* d_in, const int* in_sizes, int n_in,
                              void* d_out, int out_size, void* d_ws, size_t ws_size,
                              hipStream_t stream) {
    const int*   ids  = (const int*)d_in[0];
    const int*   sep  = (const int*)d_in[1];
    const float* emb  = (const float*)d_in[3];
    const float* g1   = (const float*)d_in[4];
    const float* b1   = (const float*)d_in[5];
    const float* W    = (const float*)d_in[6];
    const float* bias = (const float*)d_in[7];
    const float* g2   = (const float*)d_in[8];
    const float* b2   = (const float*)d_in[9];
    float* out = (float*)d_out;

    int S = out_size / (B_ * H_);                      // 128

    // workspace layout (all offsets 16B-aligned)
    char* ws = (char*)d_ws;
    __hip_bfloat16* Wp  = (__hip_bfloat16*)(ws);                         // 491,520 B
    __hip_bfloat16* G   = (__hip_bfloat16*)(ws + 491520);                // 46,891,008 B
    int*   pos  = (int*)(ws + 491520 + 46891008);                        // 262,144 B
    int*   nsep = (int*)(ws + 491520 + 46891008 + 262144);               // 256 B
    float* PE   = (float*)(ws + 491520 + 46891008 + 262144 + 256);       // 393,216 B
    (void)ws_size; (void)n_in; (void)in_sizes;

    int peBlocks = (S * H_ + 255) / 256;               // 384 for S=128
    setup    <<<120 + peBlocks + B_, 256, 0, stream>>>(W, Wp, PE, peBlocks, S, sep, pos, nsep);
    gemm_ln2 <<<VPAD / MB, 512, 0, stream>>>(emb, g1, b1, Wp, bias, g2, b2, G);
    seg_gather<<<B_ * S, 384, 0, stream>>>(ids, pos, nsep, G, PE, out, S);
}